// Round 1
// baseline (404.510 us; speedup 1.0000x reference)
//
#include <hip/hip_runtime.h>
#include <math.h>

#define BB 8
#define HH 384
#define WW 768
#define HW (HH * WW)
#define NPIX (BB * HW)

struct Bil { int x0, x1, y0, y1; float wx, wy; };

__device__ __forceinline__ Bil bilin_setup(float fx, float fy, int x, int y) {
    Bil s;
    float gx = fminf(fmaxf(fx + (float)x, 0.0f), (float)(WW - 1));
    float gy = fminf(fmaxf(fy + (float)y, 0.0f), (float)(HH - 1));
    float x0f = floorf(gx), y0f = floorf(gy);
    s.wx = gx - x0f;
    s.wy = gy - y0f;
    s.x0 = (int)x0f;
    s.y0 = (int)y0f;
    s.x1 = min(s.x0 + 1, WW - 1);
    s.y1 = min(s.y0 + 1, HH - 1);
    return s;
}

__device__ __forceinline__ float bilin(const float* __restrict__ pl, const Bil& s) {
    float v00 = pl[s.y0 * WW + s.x0];
    float v01 = pl[s.y0 * WW + s.x1];
    float v10 = pl[s.y1 * WW + s.x0];
    float v11 = pl[s.y1 * WW + s.x1];
    float iwx = 1.0f - s.wx, iwy = 1.0f - s.wy;
    return v00 * iwx * iwy + v01 * s.wx * iwy + v10 * iwx * s.wy + v11 * s.wx * s.wy;
}

__device__ __forceinline__ float gray255(float r, float g, float b) {
    return (0.2989f * r + 0.587f * g + 0.114f * b) * 255.0f;
}

__device__ __forceinline__ float robust04(float a) {
    // pow(|a| + 0.01, 0.4)
    return powf(fabsf(a) + 0.01f, 0.4f);
}

__global__ void zero_acc_kernel(float* acc) {
    if (threadIdx.x < 16) acc[threadIdx.x] = 0.0f;
}

// acc layout: 0:S_photo_fw 1:S_photo_bw 2:M_fw 3:M_bw 4:S_census_fw 5:S_census_bw
__global__ __launch_bounds__(256) void prep_kernel(
        const float* __restrict__ img1, const float* __restrict__ img2,
        const float* __restrict__ ffw, const float* __restrict__ fbw,
        float* __restrict__ acc,
        float* __restrict__ inten1, float* __restrict__ inten2,
        float* __restrict__ inten1w, float* __restrict__ inten2w,
        float* __restrict__ mask_fw, float* __restrict__ mask_bw,
        float* __restrict__ occ_out) {
    float s_pf = 0.f, s_pb = 0.f, s_mf = 0.f, s_mb = 0.f;
    for (int idx = blockIdx.x * blockDim.x + threadIdx.x; idx < NPIX;
         idx += gridDim.x * blockDim.x) {
        int b = idx / HW;
        int p = idx - b * HW;
        int y = p / WW;
        int x = p - y * WW;
        const float* i1 = img1 + b * 3 * HW;
        const float* i2 = img2 + b * 3 * HW;
        const float* f1 = ffw + b * 2 * HW;
        const float* f2 = fbw + b * 2 * HW;

        float fx = f1[p], fy = f1[HW + p];
        float bx = f2[p], by = f2[HW + p];
        float a0 = i1[p], a1 = i1[HW + p], a2 = i1[2 * HW + p];
        float c0 = i2[p], c1 = i2[HW + p], c2 = i2[2 * HW + p];

        // ---- forward direction: grid from flow_fw, gather img2 & flow_bw ----
        Bil sf = bilin_setup(fx, fy, x, y);
        float w20 = bilin(i2, sf);
        float w21 = bilin(i2 + HW, sf);
        float w22 = bilin(i2 + 2 * HW, sf);
        float wbx = bilin(f2, sf);
        float wby = bilin(f2 + HW, sf);
        inten2w[idx] = gray255(w20, w21, w22);
        float dfx = fx + wbx, dfy = fy + wby;
        float magf = dfx * dfx + dfy * dfy;
        float fmf = fx * fx + fy * fy + wbx * wbx + wby * wby;
        float occf = (magf > 0.01f * fmf + 0.5f) ? 1.0f : 0.0f;
        float mf = 1.0f - occf;
        mask_fw[idx] = mf;
        occ_out[idx] = occf;
        float pf = (robust04(a0 - w20) + robust04(a1 - w21) + robust04(a2 - w22)) * mf;

        // ---- backward direction: grid from flow_bw, gather img1 & flow_fw ----
        Bil sb = bilin_setup(bx, by, x, y);
        float w10 = bilin(i1, sb);
        float w11 = bilin(i1 + HW, sb);
        float w12 = bilin(i1 + 2 * HW, sb);
        float wfx = bilin(f1, sb);
        float wfy = bilin(f1 + HW, sb);
        inten1w[idx] = gray255(w10, w11, w12);
        float dbx = bx + wfx, dby = by + wfy;
        float magb = dbx * dbx + dby * dby;
        float fmb = bx * bx + by * by + wfx * wfx + wfy * wfy;
        float occb = (magb > 0.01f * fmb + 0.5f) ? 1.0f : 0.0f;
        float mb = 1.0f - occb;
        mask_bw[idx] = mb;
        float pb = (robust04(c0 - w10) + robust04(c1 - w11) + robust04(c2 - w12)) * mb;

        inten1[idx] = gray255(a0, a1, a2);
        inten2[idx] = gray255(c0, c1, c2);

        s_pf += pf;
        s_pb += pb;
        s_mf += mf;
        s_mb += mb;
    }

    __shared__ float sacc[4];
    if (threadIdx.x < 4) sacc[threadIdx.x] = 0.0f;
    __syncthreads();
    for (int o = 32; o > 0; o >>= 1) {
        s_pf += __shfl_down(s_pf, o, 64);
        s_pb += __shfl_down(s_pb, o, 64);
        s_mf += __shfl_down(s_mf, o, 64);
        s_mb += __shfl_down(s_mb, o, 64);
    }
    if ((threadIdx.x & 63) == 0) {
        atomicAdd(&sacc[0], s_pf);
        atomicAdd(&sacc[1], s_pb);
        atomicAdd(&sacc[2], s_mf);
        atomicAdd(&sacc[3], s_mb);
    }
    __syncthreads();
    if (threadIdx.x == 0) {
        atomicAdd(&acc[0], sacc[0]);
        atomicAdd(&acc[1], sacc[1]);
        atomicAdd(&acc[2], sacc[2]);
        atomicAdd(&acc[3], sacc[3]);
    }
}

__device__ __forceinline__ float ternary_feat(float p, float c) {
    float t = p - c;
    return t * __builtin_amdgcn_rsqf(0.81f + t * t);
}

__global__ __launch_bounds__(256) void census_kernel(
        const float* __restrict__ inten1, const float* __restrict__ inten2,
        const float* __restrict__ inten1w, const float* __restrict__ inten2w,
        const float* __restrict__ mask_fw, const float* __restrict__ mask_bw,
        float* __restrict__ acc) {
    float s_cf = 0.f, s_cb = 0.f;
    for (int idx = blockIdx.x * blockDim.x + threadIdx.x; idx < NPIX;
         idx += gridDim.x * blockDim.x) {
        int b = idx / HW;
        int p = idx - b * HW;
        int y = p / WW;
        int x = p - y * WW;
        const float* p1 = inten1 + b * HW;
        const float* p2 = inten2 + b * HW;
        const float* p1w = inten1w + b * HW;
        const float* p2w = inten2w + b * HW;

        float cc1 = p1[p];
        float cc2w = p2w[p];
        float cc2 = p2[p];
        float cc1w = p1w[p];

        float ds_f = 0.f, ds_b = 0.f;
        for (int dy = -3; dy <= 3; ++dy) {
            int yy = y + dy;
            bool yin = (yy >= 0) && (yy < HH);
            int rowbase = yy * WW;
#pragma unroll
            for (int dx = -3; dx <= 3; ++dx) {
                int xx = x + dx;
                bool in = yin && (xx >= 0) && (xx < WW);
                int q = rowbase + xx;
                float v1 = in ? p1[q] : 0.0f;
                float v2w = in ? p2w[q] : 0.0f;
                float v2 = in ? p2[q] : 0.0f;
                float v1w = in ? p1w[q] : 0.0f;
                // forward: census(img1) vs census(img2_warped)
                float t1 = ternary_feat(v1, cc1);
                float t2 = ternary_feat(v2w, cc2w);
                float df = t1 - t2;
                float d2 = df * df;
                ds_f += d2 * __builtin_amdgcn_rcpf(0.1f + d2);
                // backward: census(img2) vs census(img1_warped)
                float u1 = ternary_feat(v2, cc2);
                float u2 = ternary_feat(v1w, cc1w);
                float db = u1 - u2;
                float e2 = db * db;
                ds_b += e2 * __builtin_amdgcn_rcpf(0.1f + e2);
            }
        }
        s_cf += robust04(ds_f) * mask_fw[idx];
        s_cb += robust04(ds_b) * mask_bw[idx];
    }

    __shared__ float sacc[2];
    if (threadIdx.x < 2) sacc[threadIdx.x] = 0.0f;
    __syncthreads();
    for (int o = 32; o > 0; o >>= 1) {
        s_cf += __shfl_down(s_cf, o, 64);
        s_cb += __shfl_down(s_cb, o, 64);
    }
    if ((threadIdx.x & 63) == 0) {
        atomicAdd(&sacc[0], s_cf);
        atomicAdd(&sacc[1], s_cb);
    }
    __syncthreads();
    if (threadIdx.x == 0) {
        atomicAdd(&acc[4], sacc[0]);
        atomicAdd(&acc[5], sacc[1]);
    }
}

__global__ void finalize_kernel(const float* __restrict__ acc, float* __restrict__ out) {
    if (threadIdx.x == 0 && blockIdx.x == 0) {
        float denf = acc[2] * 2.0f + 1e-6f;
        float denb = acc[3] * 2.0f + 1e-6f;
        float photo = acc[0] / denf + acc[1] / denb;
        float cens = acc[4] / denf + acc[5] / denb;
        out[0] = photo + cens;
        out[1] = photo;
        out[2] = cens;
    }
}

extern "C" void kernel_launch(void* const* d_in, const int* in_sizes, int n_in,
                              void* d_out, int out_size, void* d_ws, size_t ws_size,
                              hipStream_t stream) {
    const float* img1 = (const float*)d_in[0];
    const float* img2 = (const float*)d_in[1];
    const float* ffw = (const float*)d_in[2];
    const float* fbw = (const float*)d_in[3];
    float* out = (float*)d_out;

    float* ws = (float*)d_ws;
    float* acc = ws;                    // 16 floats
    float* inten1 = ws + 16;            // NPIX each
    float* inten2 = inten1 + NPIX;
    float* inten1w = inten2 + NPIX;
    float* inten2w = inten1w + NPIX;
    float* mask_fw = inten2w + NPIX;
    float* mask_bw = mask_fw + NPIX;

    zero_acc_kernel<<<1, 64, 0, stream>>>(acc);
    prep_kernel<<<2048, 256, 0, stream>>>(img1, img2, ffw, fbw, acc,
                                          inten1, inten2, inten1w, inten2w,
                                          mask_fw, mask_bw, out + 3);
    census_kernel<<<4096, 256, 0, stream>>>(inten1, inten2, inten1w, inten2w,
                                            mask_fw, mask_bw, acc);
    finalize_kernel<<<1, 64, 0, stream>>>(acc, out);
}

// Round 2
// 390.698 us; speedup vs baseline: 1.0354x; 1.0354x over previous
//
#include <hip/hip_runtime.h>
#include <math.h>

#define BB 8
#define HH 384
#define WW 768
#define HW (HH * WW)
#define NPIX (BB * HW)

#define GRID_P 2048
#define CHUNK_P (NPIX / GRID_P)   // 1152
#define GRID_C 4096
#define CHUNK_C (NPIX / GRID_C)   // 576

struct Bil { int x0, x1, y0, y1; float wx, wy; };

__device__ __forceinline__ Bil bilin_setup(float fx, float fy, int x, int y) {
    Bil s;
    float gx = fminf(fmaxf(fx + (float)x, 0.0f), (float)(WW - 1));
    float gy = fminf(fmaxf(fy + (float)y, 0.0f), (float)(HH - 1));
    float x0f = floorf(gx), y0f = floorf(gy);
    s.wx = gx - x0f;
    s.wy = gy - y0f;
    s.x0 = (int)x0f;
    s.y0 = (int)y0f;
    s.x1 = min(s.x0 + 1, WW - 1);
    s.y1 = min(s.y0 + 1, HH - 1);
    return s;
}

__device__ __forceinline__ float bilin(const float* __restrict__ pl, const Bil& s) {
    float v00 = pl[s.y0 * WW + s.x0];
    float v01 = pl[s.y0 * WW + s.x1];
    float v10 = pl[s.y1 * WW + s.x0];
    float v11 = pl[s.y1 * WW + s.x1];
    float iwx = 1.0f - s.wx, iwy = 1.0f - s.wy;
    return v00 * iwx * iwy + v01 * s.wx * iwy + v10 * iwx * s.wy + v11 * s.wx * s.wy;
}

__device__ __forceinline__ float gray255(float r, float g, float b) {
    return (0.2989f * r + 0.587f * g + 0.114f * b) * 255.0f;
}

__device__ __forceinline__ float robust04(float a) {
    // pow(|a| + 0.01, 0.4) via HW log2/exp2 (arg always > 0)
    float v = fabsf(a) + 0.01f;
    return __builtin_amdgcn_exp2f(0.4f * __builtin_amdgcn_logf(v));
}

// pacc: per-block partials [GRID_P][4] = pf, pb, mf, mb
__global__ __launch_bounds__(256) void prep_kernel(
        const float* __restrict__ img1, const float* __restrict__ img2,
        const float* __restrict__ ffw, const float* __restrict__ fbw,
        float* __restrict__ pacc,
        float* __restrict__ inten1, float* __restrict__ inten2,
        float* __restrict__ inten1w, float* __restrict__ inten2w,
        float* __restrict__ mask_fw, float* __restrict__ mask_bw,
        float* __restrict__ occ_out) {
    // XCD-contiguous swizzle: XCD k (bid%8 under round-robin dispatch) gets
    // the contiguous k-th eighth of pixels == exactly one batch image, so
    // bilinear-gather cache lines are never shared across XCD L2s.
    int nb = ((blockIdx.x & 7) << 8) + (blockIdx.x >> 3);
    int start = nb * CHUNK_P;
    int end = start + CHUNK_P;

    float s_pf = 0.f, s_pb = 0.f, s_mf = 0.f, s_mb = 0.f;
    for (int idx = start + (int)threadIdx.x; idx < end; idx += 256) {
        int b = idx / HW;
        int p = idx - b * HW;
        int y = p / WW;
        int x = p - y * WW;
        const float* i1 = img1 + b * 3 * HW;
        const float* i2 = img2 + b * 3 * HW;
        const float* f1 = ffw + b * 2 * HW;
        const float* f2 = fbw + b * 2 * HW;

        float fx = f1[p], fy = f1[HW + p];
        float bx = f2[p], by = f2[HW + p];
        float a0 = i1[p], a1 = i1[HW + p], a2 = i1[2 * HW + p];
        float c0 = i2[p], c1 = i2[HW + p], c2 = i2[2 * HW + p];

        // ---- forward: grid from flow_fw, gather img2 & flow_bw ----
        Bil sf = bilin_setup(fx, fy, x, y);
        float w20 = bilin(i2, sf);
        float w21 = bilin(i2 + HW, sf);
        float w22 = bilin(i2 + 2 * HW, sf);
        float wbx = bilin(f2, sf);
        float wby = bilin(f2 + HW, sf);
        inten2w[idx] = gray255(w20, w21, w22);
        float dfx = fx + wbx, dfy = fy + wby;
        float magf = dfx * dfx + dfy * dfy;
        float fmf = fx * fx + fy * fy + wbx * wbx + wby * wby;
        float occf = (magf > 0.01f * fmf + 0.5f) ? 1.0f : 0.0f;
        float mf = 1.0f - occf;
        mask_fw[idx] = mf;
        occ_out[idx] = occf;
        float pf = (robust04(a0 - w20) + robust04(a1 - w21) + robust04(a2 - w22)) * mf;

        // ---- backward: grid from flow_bw, gather img1 & flow_fw ----
        Bil sb = bilin_setup(bx, by, x, y);
        float w10 = bilin(i1, sb);
        float w11 = bilin(i1 + HW, sb);
        float w12 = bilin(i1 + 2 * HW, sb);
        float wfx = bilin(f1, sb);
        float wfy = bilin(f1 + HW, sb);
        inten1w[idx] = gray255(w10, w11, w12);
        float dbx = bx + wfx, dby = by + wfy;
        float magb = dbx * dbx + dby * dby;
        float fmb = bx * bx + by * by + wfx * wfx + wfy * wfy;
        float occb = (magb > 0.01f * fmb + 0.5f) ? 1.0f : 0.0f;
        float mb = 1.0f - occb;
        mask_bw[idx] = mb;
        float pb = (robust04(c0 - w10) + robust04(c1 - w11) + robust04(c2 - w12)) * mb;

        inten1[idx] = gray255(a0, a1, a2);
        inten2[idx] = gray255(c0, c1, c2);

        s_pf += pf;
        s_pb += pb;
        s_mf += mf;
        s_mb += mb;
    }

    __shared__ float sacc[4];
    if (threadIdx.x < 4) sacc[threadIdx.x] = 0.0f;
    __syncthreads();
    for (int o = 32; o > 0; o >>= 1) {
        s_pf += __shfl_down(s_pf, o, 64);
        s_pb += __shfl_down(s_pb, o, 64);
        s_mf += __shfl_down(s_mf, o, 64);
        s_mb += __shfl_down(s_mb, o, 64);
    }
    if ((threadIdx.x & 63) == 0) {
        atomicAdd(&sacc[0], s_pf);
        atomicAdd(&sacc[1], s_pb);
        atomicAdd(&sacc[2], s_mf);
        atomicAdd(&sacc[3], s_mb);
    }
    __syncthreads();
    if (threadIdx.x == 0) {
        float* o = pacc + blockIdx.x * 4;
        o[0] = sacc[0];
        o[1] = sacc[1];
        o[2] = sacc[2];
        o[3] = sacc[3];
    }
}

__device__ __forceinline__ float ternary_feat(float p, float c) {
    float t = p - c;
    return t * __builtin_amdgcn_rsqf(0.81f + t * t);
}

// cacc: per-block partials [GRID_C][2] = cf, cb
__global__ __launch_bounds__(256) void census_kernel(
        const float* __restrict__ inten1, const float* __restrict__ inten2,
        const float* __restrict__ inten1w, const float* __restrict__ inten2w,
        const float* __restrict__ mask_fw, const float* __restrict__ mask_bw,
        float* __restrict__ cacc) {
    int nb = ((blockIdx.x & 7) << 9) + (blockIdx.x >> 3);
    int start = nb * CHUNK_C;
    int end = start + CHUNK_C;

    float s_cf = 0.f, s_cb = 0.f;
    for (int idx = start + (int)threadIdx.x; idx < end; idx += 256) {
        int b = idx / HW;
        int p = idx - b * HW;
        int y = p / WW;
        int x = p - y * WW;
        const float* p1 = inten1 + b * HW;
        const float* p2 = inten2 + b * HW;
        const float* p1w = inten1w + b * HW;
        const float* p2w = inten2w + b * HW;

        float cc1 = p1[p];
        float cc2w = p2w[p];
        float cc2 = p2[p];
        float cc1w = p1w[p];

        float ds_f = 0.f, ds_b = 0.f;
        for (int dy = -3; dy <= 3; ++dy) {
            int yy = y + dy;
            bool yin = (yy >= 0) && (yy < HH);
            int rowbase = yy * WW;
#pragma unroll
            for (int dx = -3; dx <= 3; ++dx) {
                int xx = x + dx;
                bool in = yin && (xx >= 0) && (xx < WW);
                int q = rowbase + xx;
                float v1 = in ? p1[q] : 0.0f;
                float v2w = in ? p2w[q] : 0.0f;
                float v2 = in ? p2[q] : 0.0f;
                float v1w = in ? p1w[q] : 0.0f;
                float t1 = ternary_feat(v1, cc1);
                float t2 = ternary_feat(v2w, cc2w);
                float df = t1 - t2;
                float d2 = df * df;
                ds_f += d2 * __builtin_amdgcn_rcpf(0.1f + d2);
                float u1 = ternary_feat(v2, cc2);
                float u2 = ternary_feat(v1w, cc1w);
                float db = u1 - u2;
                float e2 = db * db;
                ds_b += e2 * __builtin_amdgcn_rcpf(0.1f + e2);
            }
        }
        s_cf += robust04(ds_f) * mask_fw[idx];
        s_cb += robust04(ds_b) * mask_bw[idx];
    }

    __shared__ float sacc[2];
    if (threadIdx.x < 2) sacc[threadIdx.x] = 0.0f;
    __syncthreads();
    for (int o = 32; o > 0; o >>= 1) {
        s_cf += __shfl_down(s_cf, o, 64);
        s_cb += __shfl_down(s_cb, o, 64);
    }
    if ((threadIdx.x & 63) == 0) {
        atomicAdd(&sacc[0], s_cf);
        atomicAdd(&sacc[1], s_cb);
    }
    __syncthreads();
    if (threadIdx.x == 0) {
        float* o = cacc + blockIdx.x * 2;
        o[0] = sacc[0];
        o[1] = sacc[1];
    }
}

__global__ __launch_bounds__(256) void finalize_kernel(
        const float* __restrict__ pacc, const float* __restrict__ cacc,
        float* __restrict__ out) {
    float s0 = 0.f, s1 = 0.f, s2 = 0.f, s3 = 0.f, s4 = 0.f, s5 = 0.f;
    for (int i = threadIdx.x; i < GRID_P; i += 256) {
        const float* o = pacc + i * 4;
        s0 += o[0]; s1 += o[1]; s2 += o[2]; s3 += o[3];
    }
    for (int i = threadIdx.x; i < GRID_C; i += 256) {
        const float* o = cacc + i * 2;
        s4 += o[0]; s5 += o[1];
    }
    for (int o = 32; o > 0; o >>= 1) {
        s0 += __shfl_down(s0, o, 64);
        s1 += __shfl_down(s1, o, 64);
        s2 += __shfl_down(s2, o, 64);
        s3 += __shfl_down(s3, o, 64);
        s4 += __shfl_down(s4, o, 64);
        s5 += __shfl_down(s5, o, 64);
    }
    __shared__ float red[4][6];
    int w = threadIdx.x >> 6;
    if ((threadIdx.x & 63) == 0) {
        red[w][0] = s0; red[w][1] = s1; red[w][2] = s2;
        red[w][3] = s3; red[w][4] = s4; red[w][5] = s5;
    }
    __syncthreads();
    if (threadIdx.x == 0) {
        float t0 = 0.f, t1 = 0.f, t2 = 0.f, t3 = 0.f, t4 = 0.f, t5 = 0.f;
        for (int i = 0; i < 4; ++i) {
            t0 += red[i][0]; t1 += red[i][1]; t2 += red[i][2];
            t3 += red[i][3]; t4 += red[i][4]; t5 += red[i][5];
        }
        float denf = t2 * 2.0f + 1e-6f;
        float denb = t3 * 2.0f + 1e-6f;
        float photo = t0 / denf + t1 / denb;
        float cens = t4 / denf + t5 / denb;
        out[0] = photo + cens;
        out[1] = photo;
        out[2] = cens;
    }
}

extern "C" void kernel_launch(void* const* d_in, const int* in_sizes, int n_in,
                              void* d_out, int out_size, void* d_ws, size_t ws_size,
                              hipStream_t stream) {
    const float* img1 = (const float*)d_in[0];
    const float* img2 = (const float*)d_in[1];
    const float* ffw = (const float*)d_in[2];
    const float* fbw = (const float*)d_in[3];
    float* out = (float*)d_out;

    float* ws = (float*)d_ws;
    float* pacc = ws;                       // GRID_P*4
    float* cacc = pacc + GRID_P * 4;        // GRID_C*2
    float* planes = cacc + GRID_C * 2;
    float* inten1 = planes;
    float* inten2 = inten1 + NPIX;
    float* inten1w = inten2 + NPIX;
    float* inten2w = inten1w + NPIX;
    float* mask_fw = inten2w + NPIX;
    float* mask_bw = mask_fw + NPIX;

    prep_kernel<<<GRID_P, 256, 0, stream>>>(img1, img2, ffw, fbw, pacc,
                                            inten1, inten2, inten1w, inten2w,
                                            mask_fw, mask_bw, out + 3);
    census_kernel<<<GRID_C, 256, 0, stream>>>(inten1, inten2, inten1w, inten2w,
                                              mask_fw, mask_bw, cacc);
    finalize_kernel<<<1, 256, 0, stream>>>(pacc, cacc, out);
}

// Round 3
// 251.187 us; speedup vs baseline: 1.6104x; 1.5554x over previous
//
#include <hip/hip_runtime.h>
#include <math.h>

#define BB 8
#define HH 384
#define WW 768
#define HW (HH * WW)
#define NPIX (BB * HW)

#define TX 64
#define TY 16
#define HX (TX + 6)      // 70
#define HY (TY + 6)      // 22
#define LSTR 72          // LDS row stride (padded)
#define TILES_X (WW / TX)            // 12
#define TILES_Y (HH / TY)            // 24
#define NTILE (TILES_X * TILES_Y)    // 288 per image
#define GRID (NTILE * BB)            // 2304

struct Bil { int x0, x1, y0, y1; float wx, wy; };

__device__ __forceinline__ Bil bilin_setup(float fx, float fy, int x, int y) {
    Bil s;
    float gx = fminf(fmaxf(fx + (float)x, 0.0f), (float)(WW - 1));
    float gy = fminf(fmaxf(fy + (float)y, 0.0f), (float)(HH - 1));
    float x0f = floorf(gx), y0f = floorf(gy);
    s.wx = gx - x0f;
    s.wy = gy - y0f;
    s.x0 = (int)x0f;
    s.y0 = (int)y0f;
    s.x1 = min(s.x0 + 1, WW - 1);
    s.y1 = min(s.y0 + 1, HH - 1);
    return s;
}

__device__ __forceinline__ float bilin(const float* __restrict__ pl, const Bil& s) {
    float v00 = pl[s.y0 * WW + s.x0];
    float v01 = pl[s.y0 * WW + s.x1];
    float v10 = pl[s.y1 * WW + s.x0];
    float v11 = pl[s.y1 * WW + s.x1];
    float iwx = 1.0f - s.wx, iwy = 1.0f - s.wy;
    return v00 * iwx * iwy + v01 * s.wx * iwy + v10 * iwx * s.wy + v11 * s.wx * s.wy;
}

__device__ __forceinline__ float gray255(float r, float g, float b) {
    return (0.2989f * r + 0.587f * g + 0.114f * b) * 255.0f;
}

__device__ __forceinline__ float robust04(float a) {
    // pow(|a| + 0.01, 0.4) via HW log2/exp2 (arg always > 0)
    float v = fabsf(a) + 0.01f;
    return __builtin_amdgcn_exp2f(0.4f * __builtin_amdgcn_logf(v));
}

__device__ __forceinline__ float ternary_feat(float p, float c) {
    float t = p - c;
    return t * __builtin_amdgcn_rsqf(0.81f + t * t);
}

// pacc layout per block: [pf, pb, mf, mb, cf, cb]
__global__ __launch_bounds__(256) void fused_kernel(
        const float* __restrict__ img1, const float* __restrict__ img2,
        const float* __restrict__ ffw, const float* __restrict__ fbw,
        float* __restrict__ pacc, float* __restrict__ occ_out) {
    __shared__ float P1[HY][LSTR], P2[HY][LSTR], P1W[HY][LSTR], P2W[HY][LSTR];
    __shared__ float MFW[TY][TX], MBW[TY][TX];
    __shared__ float red[4][6];

    // XCD swizzle: under round-robin dispatch, XCD k gets image k's 288 tiles.
    const int img = blockIdx.x & 7;
    const int t = blockIdx.x >> 3;
    const int tyile = t / TILES_X;
    const int txile = t - tyile * TILES_X;
    const int gx0 = txile * TX - 3;
    const int gy0 = tyile * TY - 3;

    const float* i1 = img1 + img * 3 * HW;
    const float* i2 = img2 + img * 3 * HW;
    const float* f1 = ffw + img * 2 * HW;
    const float* f2 = fbw + img * 2 * HW;

    float s_pf = 0.f, s_pb = 0.f, s_mf = 0.f, s_mb = 0.f;

    // ---- Phase 1: build the 4 intensity planes (tile + halo) in LDS;
    //      masks/occ/photo for interior pixels along the way. ----
    for (int i = threadIdx.x; i < HX * HY; i += 256) {
        int ly = i / HX;
        int lx = i - ly * HX;
        int gx = gx0 + lx;
        int gy = gy0 + ly;
        bool inimg = (gx >= 0) & (gx < WW) & (gy >= 0) & (gy < HH);
        float v1 = 0.f, v2 = 0.f, v1w = 0.f, v2w = 0.f;
        if (inimg) {
            int p = gy * WW + gx;
            float fx = f1[p], fy = f1[HW + p];
            float bx = f2[p], by = f2[HW + p];
            float a0 = i1[p], a1 = i1[HW + p], a2 = i1[2 * HW + p];
            float c0 = i2[p], c1 = i2[HW + p], c2 = i2[2 * HW + p];

            Bil sf = bilin_setup(fx, fy, gx, gy);   // fw grid: gathers img2/fbw
            float w20 = bilin(i2, sf);
            float w21 = bilin(i2 + HW, sf);
            float w22 = bilin(i2 + 2 * HW, sf);
            Bil sb = bilin_setup(bx, by, gx, gy);   // bw grid: gathers img1/ffw
            float w10 = bilin(i1, sb);
            float w11 = bilin(i1 + HW, sb);
            float w12 = bilin(i1 + 2 * HW, sb);

            v1 = gray255(a0, a1, a2);
            v2 = gray255(c0, c1, c2);
            v2w = gray255(w20, w21, w22);
            v1w = gray255(w10, w11, w12);

            bool interior = (lx >= 3) & (lx < 3 + TX) & (ly >= 3) & (ly < 3 + TY);
            if (interior) {
                float wbx = bilin(f2, sf), wby = bilin(f2 + HW, sf);
                float wfx = bilin(f1, sb), wfy = bilin(f1 + HW, sb);

                float dfx = fx + wbx, dfy = fy + wby;
                float magf = dfx * dfx + dfy * dfy;
                float fmf = fx * fx + fy * fy + wbx * wbx + wby * wby;
                float occf = (magf > 0.01f * fmf + 0.5f) ? 1.0f : 0.0f;
                float mf = 1.0f - occf;

                float dbx = bx + wfx, dby = by + wfy;
                float magb = dbx * dbx + dby * dby;
                float fmb = bx * bx + by * by + wfx * wfx + wfy * wfy;
                float occb = (magb > 0.01f * fmb + 0.5f) ? 1.0f : 0.0f;
                float mb = 1.0f - occb;

                MFW[ly - 3][lx - 3] = mf;
                MBW[ly - 3][lx - 3] = mb;
                occ_out[img * HW + p] = occf;

                s_pf += (robust04(a0 - w20) + robust04(a1 - w21) + robust04(a2 - w22)) * mf;
                s_pb += (robust04(c0 - w10) + robust04(c1 - w11) + robust04(c2 - w12)) * mb;
                s_mf += mf;
                s_mb += mb;
            }
        }
        P1[ly][lx] = v1;
        P2[ly][lx] = v2;
        P1W[ly][lx] = v1w;
        P2W[ly][lx] = v2w;
    }
    __syncthreads();

    // ---- Phase 2: 49-tap census from LDS, compile-time offsets. ----
    float s_cf = 0.f, s_cb = 0.f;
    const int lx = threadIdx.x & 63;
    const int band = threadIdx.x >> 6;
    for (int rr = 0; rr < 4; ++rr) {
        int r = band * 4 + rr;          // interior row 0..15
        float cc1 = P1[r + 3][lx + 3];
        float cc2 = P2[r + 3][lx + 3];
        float cc1w = P1W[r + 3][lx + 3];
        float cc2w = P2W[r + 3][lx + 3];
        float ds_f = 0.f, ds_b = 0.f;
#pragma unroll
        for (int dy = 0; dy < 7; ++dy) {
#pragma unroll
            for (int dx = 0; dx < 7; ++dx) {
                if (dy == 3 && dx == 3) continue;   // center tap contributes 0
                float v1 = P1[r + dy][lx + dx];
                float v2w = P2W[r + dy][lx + dx];
                float v2 = P2[r + dy][lx + dx];
                float v1w = P1W[r + dy][lx + dx];
                float t1 = ternary_feat(v1, cc1);
                float t2 = ternary_feat(v2w, cc2w);
                float df = t1 - t2;
                float d2 = df * df;
                ds_f += d2 * __builtin_amdgcn_rcpf(0.1f + d2);
                float u1 = ternary_feat(v2, cc2);
                float u2 = ternary_feat(v1w, cc1w);
                float db = u1 - u2;
                float e2 = db * db;
                ds_b += e2 * __builtin_amdgcn_rcpf(0.1f + e2);
            }
        }
        s_cf += robust04(ds_f) * MFW[r][lx];
        s_cb += robust04(ds_b) * MBW[r][lx];
    }

    // ---- Reduce 6 partials across the block. ----
    for (int o = 32; o > 0; o >>= 1) {
        s_pf += __shfl_down(s_pf, o, 64);
        s_pb += __shfl_down(s_pb, o, 64);
        s_mf += __shfl_down(s_mf, o, 64);
        s_mb += __shfl_down(s_mb, o, 64);
        s_cf += __shfl_down(s_cf, o, 64);
        s_cb += __shfl_down(s_cb, o, 64);
    }
    if ((threadIdx.x & 63) == 0) {
        red[band][0] = s_pf; red[band][1] = s_pb;
        red[band][2] = s_mf; red[band][3] = s_mb;
        red[band][4] = s_cf; red[band][5] = s_cb;
    }
    __syncthreads();
    if (threadIdx.x == 0) {
        float r0 = 0.f, r1 = 0.f, r2 = 0.f, r3 = 0.f, r4 = 0.f, r5 = 0.f;
        for (int i = 0; i < 4; ++i) {
            r0 += red[i][0]; r1 += red[i][1]; r2 += red[i][2];
            r3 += red[i][3]; r4 += red[i][4]; r5 += red[i][5];
        }
        float* o = pacc + blockIdx.x * 6;
        o[0] = r0; o[1] = r1; o[2] = r2; o[3] = r3; o[4] = r4; o[5] = r5;
    }
}

__global__ __launch_bounds__(256) void finalize_kernel(
        const float* __restrict__ pacc, float* __restrict__ out) {
    float s0 = 0.f, s1 = 0.f, s2 = 0.f, s3 = 0.f, s4 = 0.f, s5 = 0.f;
    for (int i = threadIdx.x; i < GRID; i += 256) {
        const float* o = pacc + i * 6;
        s0 += o[0]; s1 += o[1]; s2 += o[2];
        s3 += o[3]; s4 += o[4]; s5 += o[5];
    }
    for (int o = 32; o > 0; o >>= 1) {
        s0 += __shfl_down(s0, o, 64);
        s1 += __shfl_down(s1, o, 64);
        s2 += __shfl_down(s2, o, 64);
        s3 += __shfl_down(s3, o, 64);
        s4 += __shfl_down(s4, o, 64);
        s5 += __shfl_down(s5, o, 64);
    }
    __shared__ float red[4][6];
    int w = threadIdx.x >> 6;
    if ((threadIdx.x & 63) == 0) {
        red[w][0] = s0; red[w][1] = s1; red[w][2] = s2;
        red[w][3] = s3; red[w][4] = s4; red[w][5] = s5;
    }
    __syncthreads();
    if (threadIdx.x == 0) {
        float t0 = 0.f, t1 = 0.f, t2 = 0.f, t3 = 0.f, t4 = 0.f, t5 = 0.f;
        for (int i = 0; i < 4; ++i) {
            t0 += red[i][0]; t1 += red[i][1]; t2 += red[i][2];
            t3 += red[i][3]; t4 += red[i][4]; t5 += red[i][5];
        }
        float denf = t2 * 2.0f + 1e-6f;
        float denb = t3 * 2.0f + 1e-6f;
        float photo = t0 / denf + t1 / denb;
        float cens = t4 / denf + t5 / denb;
        out[0] = photo + cens;
        out[1] = photo;
        out[2] = cens;
    }
}

extern "C" void kernel_launch(void* const* d_in, const int* in_sizes, int n_in,
                              void* d_out, int out_size, void* d_ws, size_t ws_size,
                              hipStream_t stream) {
    const float* img1 = (const float*)d_in[0];
    const float* img2 = (const float*)d_in[1];
    const float* ffw = (const float*)d_in[2];
    const float* fbw = (const float*)d_in[3];
    float* out = (float*)d_out;
    float* pacc = (float*)d_ws;   // GRID*6 floats

    fused_kernel<<<GRID, 256, 0, stream>>>(img1, img2, ffw, fbw, pacc, out + 3);
    finalize_kernel<<<1, 256, 0, stream>>>(pacc, out);
}